// Round 6
// baseline (478.451 us; speedup 1.0000x reference)
//
#include <hip/hip_runtime.h>
#include <math.h>

// Problem constants
#define NROWS 65536
#define DDIM  1024
#define NEXP  64
#define BM    64      // rows per block
#define BK    32      // K chunk (== one MFMA K)
#define NK    (DDIM / BK)
#define WCHUNK 12288  // shorts per k32-chunk of packed w: 3 splits * 128 n * 32 k

typedef short bf16x8 __attribute__((ext_vector_type(8)));
typedef float f32x4  __attribute__((ext_vector_type(4)));
typedef unsigned int u32x4 __attribute__((ext_vector_type(4)));

// exact-ish 3-way bf16 split, round-to-nearest (used in one-time w prep)
__device__ __forceinline__ void split3(float x, unsigned short& h,
                                       unsigned short& m, unsigned short& l) {
    unsigned u = __float_as_uint(x);
    unsigned r = u + 0x7FFFu + ((u >> 16) & 1u);
    h = (unsigned short)(r >> 16);
    float hf = __uint_as_float(r & 0xFFFF0000u);
    float r1 = x - hf;
    unsigned u2 = __float_as_uint(r1);
    unsigned r2 = u2 + 0x7FFFu + ((u2 >> 16) & 1u);
    m = (unsigned short)(r2 >> 16);
    float mf = __uint_as_float(r2 & 0xFFFF0000u);
    float r3 = r1 - mf;
    unsigned u3 = __float_as_uint(r3);
    unsigned r4 = u3 + 0x7FFFu + ((u3 >> 16) & 1u);
    l = (unsigned short)(r4 >> 16);
}

__device__ __forceinline__ float softplus_f(float x) {
    return fmaxf(x, 0.0f) + log1pf(expf(-fabsf(x)));
}

// Pack weights: wp[chunk][split][n][32] bf16, n = 0..63 route, 64..127 noise.
__global__ void __launch_bounds__(256) prep_w_kernel(
        const float* __restrict__ wr, const float* __restrict__ wn,
        short* __restrict__ wp) {
    int idx = blockIdx.x * 256 + threadIdx.x;   // 0..131071
    int n = idx >> 10;
    int k = idx & 1023;
    float v = (n < NEXP) ? wr[n * DDIM + k] : wn[(n - NEXP) * DDIM + k];
    unsigned short h, m, l;
    split3(v, h, m, l);
    int base = (k >> 5) * WCHUNK + n * 32 + (k & 31);
    wp[base]        = (short)h;
    wp[base + 4096] = (short)m;
    wp[base + 8192] = (short)l;
}

// truncation split of 8 k-consecutive fp32 into three bf16x8 MFMA A-fragments.
// Bit-identical limbs to the staged split3t path: h=trunc16(x), m=trunc16(x-h),
// l=trunc16(x-h-m). Packing via v_perm_b32 (verified bit-identical in R1/R4).
__device__ __forceinline__ void split_pack(const f32x4 a, const f32x4 b,
                                           bf16x8& H, bf16x8& M, bf16x8& L) {
    float f[8];
    *(f32x4*)&f[0] = a;
    *(f32x4*)&f[4] = b;
    u32x4 hp, mp, lp;
#pragma unroll
    for (int j = 0; j < 4; ++j) {
        float x0 = f[2 * j], x1 = f[2 * j + 1];
        unsigned u0 = __float_as_uint(x0), u1 = __float_as_uint(x1);
        hp[j] = __builtin_amdgcn_perm(u1, u0, 0x07060302u);   // [x1.hi16 : x0.hi16]
        float r0 = x0 - __uint_as_float(u0 & 0xFFFF0000u);
        float r1 = x1 - __uint_as_float(u1 & 0xFFFF0000u);
        unsigned v0 = __float_as_uint(r0), v1 = __float_as_uint(r1);
        mp[j] = __builtin_amdgcn_perm(v1, v0, 0x07060302u);
        float s0 = r0 - __uint_as_float(v0 & 0xFFFF0000u);
        float s1 = r1 - __uint_as_float(v1 & 0xFFFF0000u);
        lp[j] = __builtin_amdgcn_perm(__float_as_uint(s1), __float_as_uint(s0),
                                      0x07060302u);
    }
    H = *(bf16x8*)&hp;
    M = *(bf16x8*)&mp;
    L = *(bf16x8*)&lp;
}

__device__ __forceinline__ void top2_merge(float& v0, int& i0, float& v1, int& i1,
                                           float pv0, int pi0, float pv1, int pi1) {
    bool t0 = (pv0 > v0) || (pv0 == v0 && pi0 < i0);
    if (t0) {
        bool t1 = (v0 > pv1) || (v0 == pv1 && i0 < pi1);
        v1 = t1 ? v0 : pv1; i1 = t1 ? i0 : pi1;
        v0 = pv0; i0 = pi0;
    } else {
        bool t1 = (pv0 > v1) || (pv0 == v1 && pi0 < i1);
        if (t1) { v1 = pv0; i1 = pi0; }
    }
}

__device__ __forceinline__ void load_bf(const short* wpc, int col_r, int quad,
                                        bf16x8 (&Bf)[3][2]) {
#pragma unroll
    for (int s = 0; s < 3; ++s) {
        Bf[s][0] = *(const bf16x8*)(wpc + s * 4096 + col_r * 32 + quad * 8);
        Bf[s][1] = *(const bf16x8*)(wpc + s * 4096 + (col_r + 64) * 32 + quad * 8);
    }
}

// One mi-phase: issue the NEXT mi's raw-A loads (325-cycle lookahead: they
// drain while this phase splits + MFMAs), split the CURRENT raw-A in-register,
// run the 12-MFMA cluster. Named next/cur registers (no runtime indexing).
__device__ __forceinline__ void mi_step(
        const float* nap, f32x4& nr0, f32x4& nr1,
        const f32x4 cr0, const f32x4 cr1,
        bf16x8 (&Bc)[3][2], f32x4 (&acc2)[2]) {
    nr0 = *(const f32x4*)nap;
    nr1 = *(const f32x4*)(nap + 4);
    bf16x8 Ah, Am, Al;
    split_pack(cr0, cr1, Ah, Am, Al);
    __builtin_amdgcn_s_setprio(1);
#pragma unroll
    for (int ni = 0; ni < 2; ++ni) {
        f32x4 c = acc2[ni];
        // small-terms-first accumulation: lh, hl, mm, mh, hm, hh (== R0/R5 order)
        c = __builtin_amdgcn_mfma_f32_16x16x32_bf16(Al, Bc[0][ni], c, 0, 0, 0);
        c = __builtin_amdgcn_mfma_f32_16x16x32_bf16(Ah, Bc[2][ni], c, 0, 0, 0);
        c = __builtin_amdgcn_mfma_f32_16x16x32_bf16(Am, Bc[1][ni], c, 0, 0, 0);
        c = __builtin_amdgcn_mfma_f32_16x16x32_bf16(Am, Bc[0][ni], c, 0, 0, 0);
        c = __builtin_amdgcn_mfma_f32_16x16x32_bf16(Ah, Bc[1][ni], c, 0, 0, 0);
        c = __builtin_amdgcn_mfma_f32_16x16x32_bf16(Ah, Bc[0][ni], c, 0, 0, 0);
        acc2[ni] = c;
    }
    __builtin_amdgcn_s_setprio(0);
}

// One K-chunk: prefetch next chunk's B fragments (full-kc ~1300-cycle
// lookahead), then 4 mi-phases with rotating A-raw prefetch.
__device__ __forceinline__ void kc_body(
        int kc, const float* abase, const short* __restrict__ wp,
        int col_r, int quad,
        bf16x8 (&Bcur)[3][2], bf16x8 (&Bnxt)[3][2],
        f32x4 (&acc)[4][2],
        f32x4& arA0, f32x4& arA1, f32x4& arB0, f32x4& arB1) {
    const int kn = (kc + 1 < NK) ? kc + 1 : kc;   // clamp: last prefetch re-reads
    load_bf(wp + (size_t)kn * WCHUNK, col_r, quad, Bnxt);
    const float* a_kc = abase + kc * BK;
    // step0: consume mi0 (arA), load mi1 -> arB
    mi_step(a_kc + (size_t)16 * DDIM, arB0, arB1, arA0, arA1, Bcur, acc[0]);
    // step1: consume mi1 (arB), load mi2 -> arA
    mi_step(a_kc + (size_t)32 * DDIM, arA0, arA1, arB0, arB1, Bcur, acc[1]);
    // step2: consume mi2 (arA), load mi3 -> arB
    mi_step(a_kc + (size_t)48 * DDIM, arB0, arB1, arA0, arA1, Bcur, acc[2]);
    // step3: consume mi3 (arB), load (mi0, kc+1) -> arA
    mi_step(abase + kn * BK,          arA0, arA1, arB0, arB1, Bcur, acc[3]);
}

// Barrier-free K-loop ("R4 done right"): each wave feeds itself from global
// (x rows L1-shared by the block's 4 waves; wp chunk L1/L2-hot) with explicit
// named-register prefetch so no load is issued just-in-time (R4's failure).
// No __syncthreads / LDS in the K-loop -> no lockstep drain; waves free-run.
// launch_bounds(256,4): 128-VGPR budget; designed live set ~118 regs.
// Spill canary: WRITE_SIZE must stay ~21 MB (R2 lesson).
__global__ void __launch_bounds__(256, 4) router_kernel(
        const float* __restrict__ x, const short* __restrict__ wp,
        const float* __restrict__ eps, float* __restrict__ out) {
    // LDS only used by the epilogue: noisy[64][66] fp32 = 16896 B.
    __shared__ __align__(16) float noisy[BM * 66];
    __shared__ float4 rowout[BM];

    const int tid    = threadIdx.x;
    const int lane   = tid & 63;
    const int wv     = tid >> 6;      // wave 0..3 -> col group
    const int lane16 = lane & 15;
    const int quad   = lane >> 4;
    const int blockM = blockIdx.x * BM;

    // wave's expert columns: route col_r, noise col_r+64 in packed w
    const int col_r = wv * 16 + lane16;

    // per-lane A base: row = mi*16 + lane16, k = kc*32 + quad*8 + (0..7)
    const float* abase = x + (size_t)(blockM + lane16) * DDIM + (quad << 3);

    f32x4 acc[4][2];   // [mi][0]=route, [1]=noise
#pragma unroll
    for (int a = 0; a < 4; ++a) { acc[a][0] = (f32x4)0.0f; acc[a][1] = (f32x4)0.0f; }

    // ---- prologue: B(kc=0) and A-raw(mi=0, kc=0) in flight ----
    bf16x8 BfA[3][2], BfB[3][2];
    load_bf(wp, col_r, quad, BfA);
    f32x4 arA0 = *(const f32x4*)abase;
    f32x4 arA1 = *(const f32x4*)(abase + 4);
    f32x4 arB0, arB1;

    // ---- main loop: unroll-2 for static B double-buffer rotation ----
    for (int kc2 = 0; kc2 < NK; kc2 += 2) {
        kc_body(kc2,     abase, wp, col_r, quad, BfA, BfB, acc,
                arA0, arA1, arB0, arB1);
        kc_body(kc2 + 1, abase, wp, col_r, quad, BfB, BfA, acc,
                arA0, arA1, arB0, arB1);
    }

    // ---------------- Epilogue (unchanged from R5) ----------------
    // C-frag: row = quad*4 + v, col = lane16  [verified]
#pragma unroll
    for (int mi = 0; mi < 4; ++mi)
#pragma unroll
        for (int v = 0; v < 4; ++v) {
            int row = mi * 16 + quad * 4 + v;
            float ev = eps[(size_t)(blockM + row) * NEXP + col_r];
            noisy[row * 66 + col_r] =
                fmaf(ev, softplus_f(acc[mi][1][v]), acc[mi][0][v]);
        }
    __syncthreads();

    // top-2: 4 threads/row scan 16 cols each, merge via shfl_xor(1), shfl_xor(2)
    {
        int row = tid >> 2;
        int sub = tid & 3;
        float v0 = -INFINITY, v1 = -INFINITY;
        int   i0 = 1 << 20,   i1 = 1 << 20;
#pragma unroll
        for (int j = 0; j < 16; ++j) {
            int col = sub * 16 + j;
            float v = noisy[row * 66 + col];
            if (v > v0) { v1 = v0; i1 = i0; v0 = v; i0 = col; }
            else if (v > v1) { v1 = v; i1 = col; }
        }
#pragma unroll
        for (int d = 1; d <= 2; d <<= 1) {
            float pv0 = __shfl_xor(v0, d, 64);
            int   pi0 = __shfl_xor(i0, d, 64);
            float pv1 = __shfl_xor(v1, d, 64);
            int   pi1 = __shfl_xor(i1, d, 64);
            top2_merge(v0, i0, v1, i1, pv0, pi0, pv1, pi1);
        }
        if (sub == 0) {
            float e1  = expf(v1 - v0);
            float inv = 1.0f / (1.0f + e1);
            rowout[row] = make_float4(inv, e1 * inv,
                                      __int_as_float(i0), __int_as_float(i1));
            float* idx_out = out + (size_t)NROWS * NEXP;
            *(float2*)&idx_out[(size_t)(blockM + row) * 2] =
                make_float2((float)i0, (float)i1);
        }
    }
    __syncthreads();

    // coalesced [64][64] output tile write
#pragma unroll
    for (int it = 0; it < 4; ++it) {
        int f  = it * 256 + tid;       // float4 id 0..1023
        int m  = f >> 4;
        int c4 = (f & 15) << 2;
        float4 ro = rowout[m];
        int i0 = __float_as_int(ro.z);
        int i1 = __float_as_int(ro.w);
        float4 o;
        float* op = (float*)&o;
#pragma unroll
        for (int j = 0; j < 4; ++j) {
            int col = c4 + j;
            op[j] = (col == i0) ? ro.x : (col == i1) ? ro.y : 0.0f;
        }
        *(float4*)&out[(size_t)(blockM + m) * NEXP + c4] = o;
    }
}

extern "C" void kernel_launch(void* const* d_in, const int* in_sizes, int n_in,
                              void* d_out, int out_size, void* d_ws, size_t ws_size,
                              hipStream_t stream) {
    const float* x   = (const float*)d_in[0];
    const float* wr  = (const float*)d_in[1];
    const float* wn  = (const float*)d_in[2];
    const float* eps = (const float*)d_in[3];
    float* out = (float*)d_out;
    short* wp  = (short*)d_ws;   // 32 chunks * 12288 shorts = 1.5 MB scratch

    prep_w_kernel<<<dim3(512), dim3(256), 0, stream>>>(wr, wn, wp);
    router_kernel<<<dim3(NROWS / BM), dim3(256), 0, stream>>>(x, wp, eps, out);
}

// Round 7
// 438.860 us; speedup vs baseline: 1.0902x; 1.0902x over previous
//
#include <hip/hip_runtime.h>
#include <math.h>

// Problem constants
#define NROWS 65536
#define DDIM  1024
#define NEXP  64
#define BM    64      // rows per block; wave w owns rows [w*16, w*16+16)
#define BK    32      // K chunk (== one MFMA K)
#define NK    (DDIM / BK)
#define WCHUNK 12288  // shorts per k32-chunk of packed w: 3 splits * 4 q * 128 c * 8
#define CHUNKB (WCHUNK * 2)   // 24576 bytes per chunk

typedef short bf16x8 __attribute__((ext_vector_type(8)));
typedef float f32x4  __attribute__((ext_vector_type(4)));
typedef unsigned int u32x4 __attribute__((ext_vector_type(4)));

typedef const __attribute__((address_space(1))) unsigned int* gas_u32p;
typedef __attribute__((address_space(3))) unsigned int* las_u32p;

// exact-ish 3-way bf16 split, round-to-nearest (used in one-time w prep)
__device__ __forceinline__ void split3(float x, unsigned short& h,
                                       unsigned short& m, unsigned short& l) {
    unsigned u = __float_as_uint(x);
    unsigned r = u + 0x7FFFu + ((u >> 16) & 1u);
    h = (unsigned short)(r >> 16);
    float hf = __uint_as_float(r & 0xFFFF0000u);
    float r1 = x - hf;
    unsigned u2 = __float_as_uint(r1);
    unsigned r2 = u2 + 0x7FFFu + ((u2 >> 16) & 1u);
    m = (unsigned short)(r2 >> 16);
    float mf = __uint_as_float(r2 & 0xFFFF0000u);
    float r3 = r1 - mf;
    unsigned u3 = __float_as_uint(r3);
    unsigned r4 = u3 + 0x7FFFu + ((u3 >> 16) & 1u);
    l = (unsigned short)(r4 >> 16);
}

__device__ __forceinline__ float softplus_f(float x) {
    return fmaxf(x, 0.0f) + log1pf(expf(-fabsf(x)));
}

// Pack weights, MFMA-B-fragment-ordered so the LDS copy is linear AND the
// per-lane ds_read_b128 is bank-conflict-free:
//   wp[kc][split][quad][col][k'] shorts, col = 0..63 route, 64..127 noise,
//   k = kc*32 + quad*8 + k'.
// Read granule (16B) index = quad*128 + col -> bank-class = col mod 8 =
// lane16 mod 8 -> 2 lanes/bank = wave64 floor (conflict-free).
__global__ void __launch_bounds__(256) prep_w_kernel(
        const float* __restrict__ wr, const float* __restrict__ wn,
        short* __restrict__ wp) {
    int idx = blockIdx.x * 256 + threadIdx.x;   // 0..131071
    int n = idx >> 10;          // packed col 0..127
    int k = idx & 1023;
    float v = (n < NEXP) ? wr[n * DDIM + k] : wn[(n - NEXP) * DDIM + k];
    unsigned short h, m, l;
    split3(v, h, m, l);
    int base = (k >> 5) * WCHUNK + ((k >> 3) & 3) * 1024 + n * 8 + (k & 7);
    wp[base]        = (short)h;   // split 0 = h-plane
    wp[base + 4096] = (short)m;   // split 1 = m-plane
    wp[base + 8192] = (short)l;   // split 2 = l-plane
}

// truncation split of 8 k-consecutive fp32 into three bf16x8 MFMA A-fragments.
// Bit-identical limbs to the staged split3t path (verified R1/R4/R6):
// h=trunc16(x), m=trunc16(x-h), l=trunc16(x-h-m).
__device__ __forceinline__ void split_pack(const f32x4 a, const f32x4 b,
                                           bf16x8& H, bf16x8& M, bf16x8& L) {
    float f[8];
    *(f32x4*)&f[0] = a;
    *(f32x4*)&f[4] = b;
    u32x4 hp, mp, lp;
#pragma unroll
    for (int j = 0; j < 4; ++j) {
        float x0 = f[2 * j], x1 = f[2 * j + 1];
        unsigned u0 = __float_as_uint(x0), u1 = __float_as_uint(x1);
        hp[j] = __builtin_amdgcn_perm(u1, u0, 0x07060302u);   // [x1.hi16 : x0.hi16]
        float r0 = x0 - __uint_as_float(u0 & 0xFFFF0000u);
        float r1 = x1 - __uint_as_float(u1 & 0xFFFF0000u);
        unsigned v0 = __float_as_uint(r0), v1 = __float_as_uint(r1);
        mp[j] = __builtin_amdgcn_perm(v1, v0, 0x07060302u);
        float s0 = r0 - __uint_as_float(v0 & 0xFFFF0000u);
        float s1 = r1 - __uint_as_float(v1 & 0xFFFF0000u);
        lp[j] = __builtin_amdgcn_perm(__float_as_uint(s1), __float_as_uint(s0),
                                      0x07060302u);
    }
    H = *(bf16x8*)&hp;
    M = *(bf16x8*)&mp;
    L = *(bf16x8*)&lp;
}

__device__ __forceinline__ void top2_merge(float& v0, int& i0, float& v1, int& i1,
                                           float pv0, int pi0, float pv1, int pi1) {
    bool t0 = (pv0 > v0) || (pv0 == v0 && pi0 < i0);
    if (t0) {
        bool t1 = (v0 > pv1) || (v0 == pv1 && i0 < pi1);
        v1 = t1 ? v0 : pv1; i1 = t1 ? i0 : pi1;
        v0 = pv0; i0 = pi0;
    } else {
        bool t1 = (pv0 > v1) || (pv0 == v1 && pi0 < i1);
        if (t1) { v1 = pv0; i1 = pi0; }
    }
}

// Staged-B structure ("m97 shape"): B chunks (pre-split by prep kernel, no
// processing needed) stream into LDS via async global_load_lds - the
// pre-barrier phase is ~6 issue cycles, not a VALU split + ds_write chain.
// Each wave owns 16 rows of x exclusively: splits its own A in-register, 1x
// (no redundancy, no sharing barrier). One __syncthreads per kc.
// launch_bounds(256,4): 128-VGPR budget, designed live set ~100 regs.
// Spill canary: WRITE_SIZE must stay ~21 MB (R2 lesson).
__global__ void __launch_bounds__(256, 4) router_kernel(
        const float* __restrict__ x, const short* __restrict__ wp,
        const float* __restrict__ eps, float* __restrict__ out) {
    // Double-buffered B chunks: 2 x 24576 B = 48 KB (caps at 3 blocks/CU).
    // Epilogue reuses the same region as noisy[64][66] fp32 = 16896 B.
    __shared__ __align__(16) char smem[2 * CHUNKB];
    __shared__ float4 rowout[BM];

    const int tid    = threadIdx.x;
    const int lane   = tid & 63;
    const int wv     = tid >> 6;      // wave 0..3 -> row group (16 rows each)
    const int lane16 = lane & 15;
    const int quad   = lane >> 4;
    const int blockM = blockIdx.x * BM;

    // per-lane A source: row = wv*16 + lane16 (wave-exclusive),
    // k = kc*32 + quad*8 + (0..7)
    const float* xp = x + (size_t)(blockM + wv * 16 + lane16) * DDIM + (quad << 3);

    // staging: 256 threads x 6 x 16B = 24 KB linear copy
    const int soff = tid * 16;
#define STAGE(kn, nb) do {                                                     \
        const char* _src = (const char*)wp + (size_t)(kn) * CHUNKB + soff;     \
        char* _dst = smem + (nb) * CHUNKB + soff;                              \
        _Pragma("unroll")                                                      \
        for (int _i = 0; _i < 6; ++_i)                                         \
            __builtin_amdgcn_global_load_lds((gas_u32p)(_src + _i * 4096),     \
                (las_u32p)(_dst + _i * 4096), 16, 0, 0);                       \
    } while (0)

    // acc[ni]: cols ni*16..ni*16+15; ni 0..3 = route, 4..7 = noise
    f32x4 acc[8];
#pragma unroll
    for (int a = 0; a < 8; ++a) acc[a] = (f32x4)0.0f;

    // ---- prologue: stage kc=0, load x(kc=0) ----
    STAGE(0, 0);
    f32x4 xc0 = *(const f32x4*)xp;
    f32x4 xc1 = *(const f32x4*)(xp + 4);
    __syncthreads();

    // ---- main loop: one barrier per kc; stage(kc+1) issued first so its
    // vmcnt drains during the MFMA phase (no stall at the barrier) ----
    for (int kc = 0; kc < NK; ++kc) {
        const int cb = kc & 1;
        if (kc + 1 < NK) STAGE(kc + 1, cb ^ 1);

        // x prefetch for kc+1 (covered by this kc's MFMA phase)
        f32x4 xn0 = xc0, xn1 = xc1;
        if (kc + 1 < NK) {
            xn0 = *(const f32x4*)(xp + (kc + 1) * BK);
            xn1 = *(const f32x4*)(xp + (kc + 1) * BK + 4);
        }

        // split own A in-register (bit-identical limbs)
        bf16x8 Ah, Am, Al;
        split_pack(xc0, xc1, Ah, Am, Al);

        const short* buf = (const short*)(smem + cb * CHUNKB);
        const short* bb0 = buf + quad * 1024 + lane16 * 8;
#pragma unroll
        for (int ni = 0; ni < 8; ++ni) {
            const short* bb = bb0 + ni * 128;
            bf16x8 Bh = *(const bf16x8*)(bb);
            bf16x8 Bm = *(const bf16x8*)(bb + 4096);
            bf16x8 Bl = *(const bf16x8*)(bb + 8192);
            __builtin_amdgcn_s_setprio(1);
            f32x4 c = acc[ni];
            // small-terms-first accumulation: lh, hl, mm, mh, hm, hh (== R0)
            c = __builtin_amdgcn_mfma_f32_16x16x32_bf16(Al, Bh, c, 0, 0, 0);
            c = __builtin_amdgcn_mfma_f32_16x16x32_bf16(Ah, Bl, c, 0, 0, 0);
            c = __builtin_amdgcn_mfma_f32_16x16x32_bf16(Am, Bm, c, 0, 0, 0);
            c = __builtin_amdgcn_mfma_f32_16x16x32_bf16(Am, Bh, c, 0, 0, 0);
            c = __builtin_amdgcn_mfma_f32_16x16x32_bf16(Ah, Bm, c, 0, 0, 0);
            c = __builtin_amdgcn_mfma_f32_16x16x32_bf16(Ah, Bh, c, 0, 0, 0);
            acc[ni] = c;
            __builtin_amdgcn_s_setprio(0);
        }
        xc0 = xn0; xc1 = xn1;
        __syncthreads();   // drains this wave's STAGE issues; buf[cb^1] ready
    }

    // ---------------- Epilogue ----------------
    // C-frag: row = wv*16 + quad*4 + v, col = ni*16 + lane16  [same mapping]
    float* noisy = (float*)smem;   // [64][66], overlays staging buffers
#pragma unroll
    for (int ni = 0; ni < 4; ++ni)
#pragma unroll
        for (int v = 0; v < 4; ++v) {
            int row = wv * 16 + quad * 4 + v;
            int col = ni * 16 + lane16;
            float ev = eps[(size_t)(blockM + row) * NEXP + col];
            noisy[row * 66 + col] =
                fmaf(ev, softplus_f(acc[ni + 4][v]), acc[ni][v]);
        }
    __syncthreads();

    // top-2: 4 threads/row scan 16 cols each, merge via shfl_xor(1), shfl_xor(2)
    {
        int row = tid >> 2;
        int sub = tid & 3;
        float v0 = -INFINITY, v1 = -INFINITY;
        int   i0 = 1 << 20,   i1 = 1 << 20;
#pragma unroll
        for (int j = 0; j < 16; ++j) {
            int col = sub * 16 + j;
            float v = noisy[row * 66 + col];
            if (v > v0) { v1 = v0; i1 = i0; v0 = v; i0 = col; }
            else if (v > v1) { v1 = v; i1 = col; }
        }
#pragma unroll
        for (int d = 1; d <= 2; d <<= 1) {
            float pv0 = __shfl_xor(v0, d, 64);
            int   pi0 = __shfl_xor(i0, d, 64);
            float pv1 = __shfl_xor(v1, d, 64);
            int   pi1 = __shfl_xor(i1, d, 64);
            top2_merge(v0, i0, v1, i1, pv0, pi0, pv1, pi1);
        }
        if (sub == 0) {
            float e1  = expf(v1 - v0);
            float inv = 1.0f / (1.0f + e1);
            rowout[row] = make_float4(inv, e1 * inv,
                                      __int_as_float(i0), __int_as_float(i1));
            float* idx_out = out + (size_t)NROWS * NEXP;
            *(float2*)&idx_out[(size_t)(blockM + row) * 2] =
                make_float2((float)i0, (float)i1);
        }
    }
    __syncthreads();

    // coalesced [64][64] output tile write
#pragma unroll
    for (int it = 0; it < 4; ++it) {
        int f  = it * 256 + tid;       // float4 id 0..1023
        int m  = f >> 4;
        int c4 = (f & 15) << 2;
        float4 ro = rowout[m];
        int i0 = __float_as_int(ro.z);
        int i1 = __float_as_int(ro.w);
        float4 o;
        float* op = (float*)&o;
#pragma unroll
        for (int j = 0; j < 4; ++j) {
            int col = c4 + j;
            op[j] = (col == i0) ? ro.x : (col == i1) ? ro.y : 0.0f;
        }
        *(float4*)&out[(size_t)(blockM + m) * NEXP + c4] = o;
    }
}

extern "C" void kernel_launch(void* const* d_in, const int* in_sizes, int n_in,
                              void* d_out, int out_size, void* d_ws, size_t ws_size,
                              hipStream_t stream) {
    const float* x   = (const float*)d_in[0];
    const float* wr  = (const float*)d_in[1];
    const float* wn  = (const float*)d_in[2];
    const float* eps = (const float*)d_in[3];
    float* out = (float*)d_out;
    short* wp  = (short*)d_ws;   // 32 chunks * 12288 shorts = 1.5 MB scratch

    prep_w_kernel<<<dim3(512), dim3(256), 0, stream>>>(wr, wn, wp);
    router_kernel<<<dim3(NROWS / BM), dim3(256), 0, stream>>>(x, wp, eps, out);
}

// Round 8
// 419.630 us; speedup vs baseline: 1.1402x; 1.0458x over previous
//
#include <hip/hip_runtime.h>
#include <math.h>

// Problem constants
#define NROWS 65536
#define DDIM  1024
#define NEXP  64
#define BM    128     // rows per block; wave w owns rows [w*32, w*32+32)
#define BK    32      // K chunk (== one MFMA K)
#define NK    (DDIM / BK)
#define WCHUNK 12288  // shorts per k32-chunk of packed w: 3 splits * 4 q * 128 c * 8
#define CHUNKB (WCHUNK * 2)   // 24576 bytes per chunk

typedef short bf16x8 __attribute__((ext_vector_type(8)));
typedef float f32x4  __attribute__((ext_vector_type(4)));
typedef unsigned int u32x4 __attribute__((ext_vector_type(4)));

typedef const __attribute__((address_space(1))) unsigned int* gas_u32p;
typedef __attribute__((address_space(3))) unsigned int* las_u32p;

// exact-ish 3-way bf16 split, round-to-nearest (used in one-time w prep)
__device__ __forceinline__ void split3(float x, unsigned short& h,
                                       unsigned short& m, unsigned short& l) {
    unsigned u = __float_as_uint(x);
    unsigned r = u + 0x7FFFu + ((u >> 16) & 1u);
    h = (unsigned short)(r >> 16);
    float hf = __uint_as_float(r & 0xFFFF0000u);
    float r1 = x - hf;
    unsigned u2 = __float_as_uint(r1);
    unsigned r2 = u2 + 0x7FFFu + ((u2 >> 16) & 1u);
    m = (unsigned short)(r2 >> 16);
    float mf = __uint_as_float(r2 & 0xFFFF0000u);
    float r3 = r1 - mf;
    unsigned u3 = __float_as_uint(r3);
    unsigned r4 = u3 + 0x7FFFu + ((u3 >> 16) & 1u);
    l = (unsigned short)(r4 >> 16);
}

__device__ __forceinline__ float softplus_f(float x) {
    return fmaxf(x, 0.0f) + log1pf(expf(-fabsf(x)));
}

// Pack weights, MFMA-B-fragment-ordered (identical to R7):
//   wp[kc][split][quad][col][k'] shorts, col = 0..63 route, 64..127 noise,
//   k = kc*32 + quad*8 + k'.
__global__ void __launch_bounds__(256) prep_w_kernel(
        const float* __restrict__ wr, const float* __restrict__ wn,
        short* __restrict__ wp) {
    int idx = blockIdx.x * 256 + threadIdx.x;   // 0..131071
    int n = idx >> 10;          // packed col 0..127
    int k = idx & 1023;
    float v = (n < NEXP) ? wr[n * DDIM + k] : wn[(n - NEXP) * DDIM + k];
    unsigned short h, m, l;
    split3(v, h, m, l);
    int base = (k >> 5) * WCHUNK + ((k >> 3) & 3) * 1024 + n * 8 + (k & 7);
    wp[base]        = (short)h;   // split 0 = h-plane
    wp[base + 4096] = (short)m;   // split 1 = m-plane
    wp[base + 8192] = (short)l;   // split 2 = l-plane
}

// truncation split of 8 k-consecutive fp32 into three bf16x8 MFMA A-fragments.
// Bit-identical limbs to the staged split3t path (verified R1/R4/R6/R7):
// h=trunc16(x), m=trunc16(x-h), l=trunc16(x-h-m).
__device__ __forceinline__ void split_pack(const f32x4 a, const f32x4 b,
                                           bf16x8& H, bf16x8& M, bf16x8& L) {
    float f[8];
    *(f32x4*)&f[0] = a;
    *(f32x4*)&f[4] = b;
    u32x4 hp, mp, lp;
#pragma unroll
    for (int j = 0; j < 4; ++j) {
        float x0 = f[2 * j], x1 = f[2 * j + 1];
        unsigned u0 = __float_as_uint(x0), u1 = __float_as_uint(x1);
        hp[j] = __builtin_amdgcn_perm(u1, u0, 0x07060302u);   // [x1.hi16 : x0.hi16]
        float r0 = x0 - __uint_as_float(u0 & 0xFFFF0000u);
        float r1 = x1 - __uint_as_float(u1 & 0xFFFF0000u);
        unsigned v0 = __float_as_uint(r0), v1 = __float_as_uint(r1);
        mp[j] = __builtin_amdgcn_perm(v1, v0, 0x07060302u);
        float s0 = r0 - __uint_as_float(v0 & 0xFFFF0000u);
        float s1 = r1 - __uint_as_float(v1 & 0xFFFF0000u);
        lp[j] = __builtin_amdgcn_perm(__float_as_uint(s1), __float_as_uint(s0),
                                      0x07060302u);
    }
    H = *(bf16x8*)&hp;
    M = *(bf16x8*)&mp;
    L = *(bf16x8*)&lp;
}

__device__ __forceinline__ void top2_merge(float& v0, int& i0, float& v1, int& i1,
                                           float pv0, int pi0, float pv1, int pi1) {
    bool t0 = (pv0 > v0) || (pv0 == v0 && pi0 < i0);
    if (t0) {
        bool t1 = (v0 > pv1) || (v0 == pv1 && i0 < pi1);
        v1 = t1 ? v0 : pv1; i1 = t1 ? i0 : pi1;
        v0 = pv0; i0 = pi0;
    } else {
        bool t1 = (pv0 > v1) || (pv0 == v1 && pi0 < i1);
        if (t1) { v1 = pv0; i1 = pi0; }
    }
}

// BM=128 staged-B structure: each wave owns 32 rows (2 mi-tiles) so the 24
// B-fragments read from LDS per kc feed 96 MFMAs (2x the rows of R7 per
// fragment) - per-row LDS traffic and barrier count both halve vs R7.
// B streams in by async global_load_lds (no L1 thrash, ~zero pre-barrier
// work); A is split in-register once per element (VALU floor ~9 us).
// launch_bounds(256,2): 256-VGPR budget for the ~155-reg live set; only 2
// waves/SIMD needed (grid 512 = 2 blocks/CU). Spill canary: WRITE_SIZE.
__global__ void __launch_bounds__(256, 2) router_kernel(
        const float* __restrict__ x, const short* __restrict__ wp,
        const float* __restrict__ eps, float* __restrict__ out) {
    // Double-buffered B chunks: 2 x 24576 B = 48 KB.
    // Epilogue reuses the same region as noisy[128][66] fp32 = 33792 B.
    __shared__ __align__(16) char smem[2 * CHUNKB];
    __shared__ float4 rowout[BM];

    const int tid    = threadIdx.x;
    const int lane   = tid & 63;
    const int wv     = tid >> 6;      // wave 0..3 -> 32-row group
    const int lane16 = lane & 15;
    const int quad   = lane >> 4;
    const int blockM = blockIdx.x * BM;

    // per-lane A sources: mi=0 row = wv*32 + lane16, mi=1 row = +16,
    // k = kc*32 + quad*8 + (0..7)
    const float* xpa = x + (size_t)(blockM + wv * 32 + lane16) * DDIM + (quad << 3);
    const float* xpb = xpa + (size_t)16 * DDIM;

    // staging: 256 threads x 6 x 16B = 24 KB linear copy
    const int soff = tid * 16;
#define STAGE(kn, nb) do {                                                     \
        const char* _src = (const char*)wp + (size_t)(kn) * CHUNKB + soff;     \
        char* _dst = smem + (nb) * CHUNKB + soff;                              \
        _Pragma("unroll")                                                      \
        for (int _i = 0; _i < 6; ++_i)                                         \
            __builtin_amdgcn_global_load_lds((gas_u32p)(_src + _i * 4096),     \
                (las_u32p)(_dst + _i * 4096), 16, 0, 0);                       \
    } while (0)

    // acc[mi][ni]: rows wv*32+mi*16.., cols ni*16..; ni 0..3 route, 4..7 noise
    f32x4 acc[2][8];
#pragma unroll
    for (int a = 0; a < 2; ++a)
#pragma unroll
        for (int b = 0; b < 8; ++b) acc[a][b] = (f32x4)0.0f;

    // ---- prologue: stage kc=0, load x(kc=0) ----
    STAGE(0, 0);
    f32x4 xa0 = *(const f32x4*)xpa;
    f32x4 xa1 = *(const f32x4*)(xpa + 4);
    f32x4 xb0 = *(const f32x4*)xpb;
    f32x4 xb1 = *(const f32x4*)(xpb + 4);
    __syncthreads();

    // ---- main loop: one barrier per kc; STAGE(kc+1) issued first so its
    // vmcnt drains during the 96-MFMA phase (no stall at the barrier) ----
    for (int kc = 0; kc < NK; ++kc) {
        const int cb = kc & 1;
        if (kc + 1 < NK) STAGE(kc + 1, cb ^ 1);

        // x prefetch for kc+1 (covered by this kc's MFMA phase)
        f32x4 na0 = xa0, na1 = xa1, nb0 = xb0, nb1 = xb1;
        if (kc + 1 < NK) {
            const int o = (kc + 1) * BK;
            na0 = *(const f32x4*)(xpa + o);
            na1 = *(const f32x4*)(xpa + o + 4);
            nb0 = *(const f32x4*)(xpb + o);
            nb1 = *(const f32x4*)(xpb + o + 4);
        }

        // split own A in-register (bit-identical limbs), both mi-tiles
        bf16x8 A0h, A0m, A0l, A1h, A1m, A1l;
        split_pack(xa0, xa1, A0h, A0m, A0l);
        split_pack(xb0, xb1, A1h, A1m, A1l);

        const short* buf = (const short*)(smem + cb * CHUNKB);
        const short* bb0 = buf + quad * 1024 + lane16 * 8;
#pragma unroll
        for (int ni = 0; ni < 8; ++ni) {
            const short* bb = bb0 + ni * 128;
            bf16x8 Bh = *(const bf16x8*)(bb);
            bf16x8 Bm = *(const bf16x8*)(bb + 4096);
            bf16x8 Bl = *(const bf16x8*)(bb + 8192);
            __builtin_amdgcn_s_setprio(1);
            {
                f32x4 c = acc[0][ni];
                // small-terms-first accumulation: lh, hl, mm, mh, hm, hh
                c = __builtin_amdgcn_mfma_f32_16x16x32_bf16(A0l, Bh, c, 0, 0, 0);
                c = __builtin_amdgcn_mfma_f32_16x16x32_bf16(A0h, Bl, c, 0, 0, 0);
                c = __builtin_amdgcn_mfma_f32_16x16x32_bf16(A0m, Bm, c, 0, 0, 0);
                c = __builtin_amdgcn_mfma_f32_16x16x32_bf16(A0m, Bh, c, 0, 0, 0);
                c = __builtin_amdgcn_mfma_f32_16x16x32_bf16(A0h, Bm, c, 0, 0, 0);
                c = __builtin_amdgcn_mfma_f32_16x16x32_bf16(A0h, Bh, c, 0, 0, 0);
                acc[0][ni] = c;
            }
            {
                f32x4 c = acc[1][ni];
                c = __builtin_amdgcn_mfma_f32_16x16x32_bf16(A1l, Bh, c, 0, 0, 0);
                c = __builtin_amdgcn_mfma_f32_16x16x32_bf16(A1h, Bl, c, 0, 0, 0);
                c = __builtin_amdgcn_mfma_f32_16x16x32_bf16(A1m, Bm, c, 0, 0, 0);
                c = __builtin_amdgcn_mfma_f32_16x16x32_bf16(A1m, Bh, c, 0, 0, 0);
                c = __builtin_amdgcn_mfma_f32_16x16x32_bf16(A1h, Bm, c, 0, 0, 0);
                c = __builtin_amdgcn_mfma_f32_16x16x32_bf16(A1h, Bh, c, 0, 0, 0);
                acc[1][ni] = c;
            }
            __builtin_amdgcn_s_setprio(0);
        }
        xa0 = na0; xa1 = na1; xb0 = nb0; xb1 = nb1;
        __syncthreads();   // drains this wave's STAGE issues; buf[cb^1] ready
    }

    // ---------------- Epilogue ----------------
    // C-frag: row = wv*32 + mi*16 + quad*4 + v, col = ni*16 + lane16
    float* noisy = (float*)smem;   // [128][66], overlays staging buffers
#pragma unroll
    for (int mi = 0; mi < 2; ++mi)
#pragma unroll
        for (int ni = 0; ni < 4; ++ni)
#pragma unroll
            for (int v = 0; v < 4; ++v) {
                int row = wv * 32 + mi * 16 + quad * 4 + v;
                int col = ni * 16 + lane16;
                float ev = eps[(size_t)(blockM + row) * NEXP + col];
                noisy[row * 66 + col] =
                    fmaf(ev, softplus_f(acc[mi][ni + 4][v]), acc[mi][ni][v]);
            }
    __syncthreads();

    // top-2: 2 threads/row scan 32 cols each (ascending -> same tie behavior
    // as before: strict > keeps lowest index), merge via shfl_xor(1)
    {
        int row = tid >> 1;
        int sub = tid & 1;
        float v0 = -INFINITY, v1 = -INFINITY;
        int   i0 = 1 << 20,   i1 = 1 << 20;
#pragma unroll
        for (int j = 0; j < 32; ++j) {
            int col = sub * 32 + j;
            float v = noisy[row * 66 + col];
            if (v > v0) { v1 = v0; i1 = i0; v0 = v; i0 = col; }
            else if (v > v1) { v1 = v; i1 = col; }
        }
        {
            float pv0 = __shfl_xor(v0, 1, 64);
            int   pi0 = __shfl_xor(i0, 1, 64);
            float pv1 = __shfl_xor(v1, 1, 64);
            int   pi1 = __shfl_xor(i1, 1, 64);
            top2_merge(v0, i0, v1, i1, pv0, pi0, pv1, pi1);
        }
        if (sub == 0) {
            float e1  = expf(v1 - v0);
            float inv = 1.0f / (1.0f + e1);
            rowout[row] = make_float4(inv, e1 * inv,
                                      __int_as_float(i0), __int_as_float(i1));
            float* idx_out = out + (size_t)NROWS * NEXP;
            *(float2*)&idx_out[(size_t)(blockM + row) * 2] =
                make_float2((float)i0, (float)i1);
        }
    }
    __syncthreads();

    // coalesced [128][64] output tile write
#pragma unroll
    for (int it = 0; it < 8; ++it) {
        int f  = it * 256 + tid;       // float4 id 0..2047
        int m  = f >> 4;
        int c4 = (f & 15) << 2;
        float4 ro = rowout[m];
        int i0 = __float_as_int(ro.z);
        int i1 = __float_as_int(ro.w);
        float4 o;
        float* op = (float*)&o;
#pragma unroll
        for (int j = 0; j < 4; ++j) {
            int col = c4 + j;
            op[j] = (col == i0) ? ro.x : (col == i1) ? ro.y : 0.0f;
        }
        *(float4*)&out[(size_t)(blockM + m) * NEXP + c4] = o;
    }
}

extern "C" void kernel_launch(void* const* d_in, const int* in_sizes, int n_in,
                              void* d_out, int out_size, void* d_ws, size_t ws_size,
                              hipStream_t stream) {
    const float* x   = (const float*)d_in[0];
    const float* wr  = (const float*)d_in[1];
    const float* wn  = (const float*)d_in[2];
    const float* eps = (const float*)d_in[3];
    float* out = (float*)d_out;
    short* wp  = (short*)d_ws;   // 32 chunks * 12288 shorts = 1.5 MB scratch

    prep_w_kernel<<<dim3(512), dim3(256), 0, stream>>>(wr, wn, wp);
    router_kernel<<<dim3(NROWS / BM), dim3(256), 0, stream>>>(x, wp, eps, out);
}